// Round 1
// baseline (379.501 us; speedup 1.0000x reference)
//
#include <hip/hip_runtime.h>
#include <cstdint>

typedef unsigned short u16;
typedef __attribute__((ext_vector_type(8))) short bf16x8;
typedef __attribute__((ext_vector_type(4))) float f32x4;

#define DIM_ 2048
#define S_   2048
#define B_   2
#define H_   16
#define HD_  128
#define M_   (B_ * S_)  // 4096

// ---------- scalar bf16 helpers (RNE) ----------
__device__ __forceinline__ u16 f2b(float f) {
  union { float f; uint32_t u; } v; v.f = f;
  uint32_t u = v.u;
  return (u16)((u + 0x7FFFu + ((u >> 16) & 1u)) >> 16);
}
__device__ __forceinline__ float b2f(u16 h) {
  union { uint32_t u; float f; } v; v.u = ((uint32_t)h) << 16;
  return v.f;
}

// ---------- global -> LDS async copy (16B per lane, wave-uniform LDS base) ----------
typedef __attribute__((address_space(3))) u16 lds_u16_t;
typedef __attribute__((address_space(1))) const u16 glob_u16_t;

__device__ __forceinline__ void gload16(const u16* g, u16* l) {
  __builtin_amdgcn_global_load_lds((glob_u16_t*)g, (lds_u16_t*)l, 16, 0, 0);
}

// ---------- fp32 -> bf16 convert ----------
__global__ void convert_kernel(const float* __restrict__ in, u16* __restrict__ out, int n) {
  int i = (blockIdx.x * blockDim.x + threadIdx.x) * 4;
  int stride = gridDim.x * blockDim.x * 4;
  for (; i < n; i += stride) {
    float4 v = *reinterpret_cast<const float4*>(in + i);
    uint64_t p = (uint64_t)f2b(v.x) | ((uint64_t)f2b(v.y) << 16) |
                 ((uint64_t)f2b(v.z) << 32) | ((uint64_t)f2b(v.w) << 48);
    *reinterpret_cast<uint64_t*>(out + i) = p;
  }
}

// ---------- RoPE tables: cos/sin [S][64] fp32 ----------
__global__ void rope_table_kernel(float* __restrict__ cosT, float* __restrict__ sinT) {
  int i = blockIdx.x * blockDim.x + threadIdx.x;
  if (i >= S_ * 64) return;
  int s = i >> 6, d = i & 63;
  float inv = powf(10000.0f, -(float)d * (1.0f / 64.0f));
  float ang = (float)s * inv;
  cosT[i] = cosf(ang);
  sinT[i] = sinf(ang);
}

// ---------- RoPE apply (in-place, rotate-half, D=128) ----------
__global__ void rope_apply_kernel(u16* __restrict__ buf, const float* __restrict__ cosT,
                                  const float* __restrict__ sinT) {
  int i = blockIdx.x * blockDim.x + threadIdx.x;  // over B*S*H*64
  if (i >= B_ * S_ * H_ * 64) return;
  int d = i & 63;
  int h = (i >> 6) & (H_ - 1);
  int row = i >> 10;        // b*S + s
  int s = row & (S_ - 1);
  u16* p = buf + (size_t)row * DIM_ + h * HD_ + d;
  float t1 = b2f(p[0]);
  float t2 = b2f(p[64]);
  float c = cosT[s * 64 + d];
  float sn = sinT[s * 64 + d];
  p[0]  = f2b(t1 * c - t2 * sn);
  p[64] = f2b(t2 * c + t1 * sn);
}

// ---------- GEMM: C[M,2048] = A[M,2048]bf16 @ W[2048,2048]^T bf16 ----------
// 128x128 tile, BK=32, 256 threads = 4 waves, each wave 32 rows x 128 cols.
template <bool OUTF32>
__device__ __forceinline__ void gemm_body(const u16* __restrict__ A, const u16* __restrict__ W,
                                          u16* __restrict__ Cb, float* __restrict__ Cf) {
  __shared__ __align__(16) u16 aT[128 * 32];
  __shared__ __align__(16) u16 bT[128 * 32];
  const int t = threadIdx.x;
  const int lane = t & 63;
  const int w = t >> 6;
  const int l15 = lane & 15;
  const int lg = lane >> 4;
  const int m0 = blockIdx.y * 128;
  const int n0 = blockIdx.x * 128;

  const f32x4 zero4 = {0.f, 0.f, 0.f, 0.f};
  f32x4 acc[2][8];
#pragma unroll
  for (int i = 0; i < 2; ++i)
#pragma unroll
    for (int j = 0; j < 8; ++j) acc[i][j] = zero4;

  for (int k0 = 0; k0 < DIM_; k0 += 32) {
    __syncthreads();
#pragma unroll
    for (int pass = 0; pass < 2; ++pass) {
      const int cb = pass * 256 + w * 64;   // wave-uniform chunk base
      const int cid = cb + lane;            // per-lane chunk id (16B chunks)
      const int row = cid >> 2;             // 4 chunks per 32-elem row
      const int col = (cid & 3) * 8;
      gload16(A + (size_t)(m0 + row) * DIM_ + k0 + col, aT + cb * 8);
      gload16(W + (size_t)(n0 + row) * DIM_ + k0 + col, bT + cb * 8);
    }
    __syncthreads();  // drains vmcnt -> LDS ready
    bf16x8 af[2], bf[8];
#pragma unroll
    for (int mi = 0; mi < 2; ++mi)
      af[mi] = *(const bf16x8*)(aT + (w * 32 + mi * 16 + l15) * 32 + lg * 8);
#pragma unroll
    for (int ni = 0; ni < 8; ++ni)
      bf[ni] = *(const bf16x8*)(bT + (ni * 16 + l15) * 32 + lg * 8);
#pragma unroll
    for (int mi = 0; mi < 2; ++mi)
#pragma unroll
      for (int ni = 0; ni < 8; ++ni)
        acc[mi][ni] =
            __builtin_amdgcn_mfma_f32_16x16x32_bf16(af[mi], bf[ni], acc[mi][ni], 0, 0, 0);
  }
  // epilogue: D row=(lane>>4)*4+r, col=lane&15 within each 16x16 frag
#pragma unroll
  for (int mi = 0; mi < 2; ++mi)
#pragma unroll
    for (int ni = 0; ni < 8; ++ni) {
      const int row = m0 + w * 32 + mi * 16 + lg * 4;
      const int col = n0 + ni * 16 + l15;
#pragma unroll
      for (int r = 0; r < 4; ++r) {
        if (OUTF32)
          Cf[(size_t)(row + r) * DIM_ + col] = acc[mi][ni][r];
        else
          Cb[(size_t)(row + r) * DIM_ + col] = f2b(acc[mi][ni][r]);
      }
    }
}

__global__ __launch_bounds__(256, 2) void gemm_qkv_kernel(
    const u16* __restrict__ xb, const u16* __restrict__ wqb, const u16* __restrict__ wkb,
    const u16* __restrict__ wvb, u16* __restrict__ qb, u16* __restrict__ kb,
    u16* __restrict__ vb) {
  const u16* W;
  u16* O;
  if (blockIdx.z == 0) { W = wqb; O = qb; }
  else if (blockIdx.z == 1) { W = wkb; O = kb; }
  else { W = wvb; O = vb; }
  gemm_body<false>(xb, W, O, nullptr);
}

__global__ __launch_bounds__(256, 2) void gemm_out_kernel(const u16* __restrict__ A,
                                                          const u16* __restrict__ W,
                                                          float* __restrict__ C) {
  gemm_body<true>(A, W, nullptr, C);
}

// ---------- causal flash attention ----------
// block = (qt, h, b): 128 q-rows, 4 waves x 32 rows. KV tiles of 64.
__global__ __launch_bounds__(256, 1) void attn_kernel(const u16* __restrict__ q,
                                                      const u16* __restrict__ k,
                                                      const u16* __restrict__ v,
                                                      u16* __restrict__ ao) {
  __shared__ __align__(16) u16 kT[64 * 136];    // K tile [64 k][128 d] padded
  __shared__ __align__(16) u16 vT[128 * 72];    // V tile transposed [128 d][64 k] padded
  __shared__ __align__(16) u16 pT[4][32 * 72];  // per-wave P [32 q][64 k] padded

  const int qt = blockIdx.x;
  const int h  = blockIdx.y;
  const int b  = blockIdx.z;
  const int t = threadIdx.x;
  const int lane = t & 63;
  const int w = t >> 6;
  const int l15 = lane & 15;
  const int lg = lane >> 4;
  const float scale = 0.08838834764831845f;  // 1/sqrt(128)

  const int qrow0 = qt * 128 + w * 32;

  // Q fragments in registers: rows qrow0..+31, full d=128
  bf16x8 qf[2][4];
#pragma unroll
  for (int mi = 0; mi < 2; ++mi)
#pragma unroll
    for (int kk = 0; kk < 4; ++kk)
      qf[mi][kk] = *(const bf16x8*)(q + (size_t)(b * S_ + qrow0 + mi * 16 + l15) * DIM_ +
                                    h * HD_ + kk * 32 + lg * 8);

  const f32x4 zero4 = {0.f, 0.f, 0.f, 0.f};
  f32x4 accO[2][8];
#pragma unroll
  for (int i = 0; i < 2; ++i)
#pragma unroll
    for (int j = 0; j < 8; ++j) accO[i][j] = zero4;
  float mrow[2][4], lrow[2][4];
#pragma unroll
  for (int i = 0; i < 2; ++i)
#pragma unroll
    for (int r = 0; r < 4; ++r) { mrow[i][r] = -1e30f; lrow[i][r] = 0.f; }

  const int tmax = 2 * qt + 1;  // causal: only tiles overlapping k <= q
  for (int tt = 0; tt <= tmax; ++tt) {
    __syncthreads();  // previous tile's PV reads done before overwrite
    // stage K tile [64][128] -> kT [64][136]
#pragma unroll
    for (int p = 0; p < 4; ++p) {
      const int cid = p * 256 + t;
      const int kr = cid >> 4;
      const int kc = (cid & 15) * 8;
      *(bf16x8*)(kT + kr * 136 + kc) =
          *(const bf16x8*)(k + (size_t)(b * S_ + tt * 64 + kr) * DIM_ + h * HD_ + kc);
    }
    // stage V tile transposed: vT[d][kk]
#pragma unroll
    for (int p = 0; p < 4; ++p) {
      const int cid = p * 256 + t;
      const int vr = cid & 63;          // lane-consecutive rows -> conflict-free writes
      const int vc = (cid >> 6) * 8;
      bf16x8 vv = *(const bf16x8*)(v + (size_t)(b * S_ + tt * 64 + vr) * DIM_ + h * HD_ + vc);
#pragma unroll
      for (int j = 0; j < 8; ++j) vT[(vc + j) * 72 + vr] = (u16)vv[j];
    }
    __syncthreads();

    // S = Q K^T : accS[mi][nk], q-rows x 64 k-cols
    f32x4 accS[2][4];
#pragma unroll
    for (int i = 0; i < 2; ++i)
#pragma unroll
      for (int j = 0; j < 4; ++j) accS[i][j] = zero4;
#pragma unroll
    for (int kk = 0; kk < 4; ++kk) {
      bf16x8 kf[4];
#pragma unroll
      for (int nk = 0; nk < 4; ++nk)
        kf[nk] = *(const bf16x8*)(kT + (nk * 16 + l15) * 136 + kk * 32 + lg * 8);
#pragma unroll
      for (int mi = 0; mi < 2; ++mi)
#pragma unroll
        for (int nk = 0; nk < 4; ++nk)
          accS[mi][nk] =
              __builtin_amdgcn_mfma_f32_16x16x32_bf16(qf[mi][kk], kf[nk], accS[mi][nk], 0, 0, 0);
    }

    // online softmax (fp32). lane holds rows lg*4+r of frag mi, col l15+16*nk.
#pragma unroll
    for (int mi = 0; mi < 2; ++mi)
#pragma unroll
      for (int r = 0; r < 4; ++r) {
        const int qg = qrow0 + mi * 16 + lg * 4 + r;
        float sv[4];
        float rmax = -1e30f;
#pragma unroll
        for (int nk = 0; nk < 4; ++nk) {
          const int kg = tt * 64 + nk * 16 + l15;
          float x = accS[mi][nk][r] * scale;
          x = (kg <= qg) ? x : -1e30f;
          sv[nk] = x;
          rmax = fmaxf(rmax, x);
        }
#pragma unroll
        for (int mk = 1; mk < 16; mk <<= 1) rmax = fmaxf(rmax, __shfl_xor(rmax, mk));
        const float newm = fmaxf(mrow[mi][r], rmax);
        float rsum = 0.f;
#pragma unroll
        for (int nk = 0; nk < 4; ++nk) {
          const float pv = __expf(sv[nk] - newm);
          sv[nk] = pv;
          rsum += pv;
        }
#pragma unroll
        for (int mk = 1; mk < 16; mk <<= 1) rsum += __shfl_xor(rsum, mk);
        const float osc = __expf(mrow[mi][r] - newm);
        lrow[mi][r] = lrow[mi][r] * osc + rsum;
        mrow[mi][r] = newm;
#pragma unroll
        for (int nd = 0; nd < 8; ++nd) accO[mi][nd][r] *= osc;
#pragma unroll
        for (int nk = 0; nk < 4; ++nk)
          pT[w][(mi * 16 + lg * 4 + r) * 72 + nk * 16 + l15] = f2b(sv[nk]);
      }
    __syncthreads();  // P visibility (cross-lane through LDS) + keep waves together

    // O += P V : contraction over 64 k in 2 steps of 32
#pragma unroll
    for (int s2 = 0; s2 < 2; ++s2) {
      bf16x8 pf[2];
#pragma unroll
      for (int mi = 0; mi < 2; ++mi)
        pf[mi] = *(const bf16x8*)(&pT[w][(mi * 16 + l15) * 72 + s2 * 32 + lg * 8]);
#pragma unroll
      for (int nd = 0; nd < 8; ++nd) {
        const bf16x8 vf = *(const bf16x8*)(vT + (nd * 16 + l15) * 72 + s2 * 32 + lg * 8);
#pragma unroll
        for (int mi = 0; mi < 2; ++mi)
          accO[mi][nd] =
              __builtin_amdgcn_mfma_f32_16x16x32_bf16(pf[mi], vf, accO[mi][nd], 0, 0, 0);
      }
    }
  }

  // normalize + store bf16
#pragma unroll
  for (int mi = 0; mi < 2; ++mi)
#pragma unroll
    for (int nd = 0; nd < 8; ++nd) {
      const int row = b * S_ + qrow0 + mi * 16 + lg * 4;
      const int col = h * HD_ + nd * 16 + l15;
#pragma unroll
      for (int r = 0; r < 4; ++r)
        ao[(size_t)(row + r) * DIM_ + col] = f2b(accO[mi][nd][r] / lrow[mi][r]);
    }
}

// ---------- launch ----------
extern "C" void kernel_launch(void* const* d_in, const int* in_sizes, int n_in,
                              void* d_out, int out_size, void* d_ws, size_t ws_size,
                              hipStream_t stream) {
  const float* x  = (const float*)d_in[0];
  // d_in[1] is the causal mask -- deterministic tril, not needed
  const float* wq = (const float*)d_in[2];
  const float* wk = (const float*)d_in[3];
  const float* wv = (const float*)d_in[4];
  const float* wo = (const float*)d_in[5];

  char* ws = (char*)d_ws;
  size_t off = 0;
  auto carve = [&](size_t bytes) { char* p = ws + off; off += bytes; return p; };
  u16* xb   = (u16*)carve((size_t)M_ * DIM_ * 2);
  u16* wqb  = (u16*)carve((size_t)DIM_ * DIM_ * 2);
  u16* wkb  = (u16*)carve((size_t)DIM_ * DIM_ * 2);
  u16* wvb  = (u16*)carve((size_t)DIM_ * DIM_ * 2);
  u16* wob  = (u16*)carve((size_t)DIM_ * DIM_ * 2);
  u16* qb   = (u16*)carve((size_t)M_ * DIM_ * 2);
  u16* kb   = (u16*)carve((size_t)M_ * DIM_ * 2);
  u16* vb   = (u16*)carve((size_t)M_ * DIM_ * 2);
  u16* aob  = (u16*)carve((size_t)M_ * DIM_ * 2);
  float* cosT = (float*)carve((size_t)S_ * 64 * 4);
  float* sinT = (float*)carve((size_t)S_ * 64 * 4);
  if (off > ws_size) return;  // workspace too small; fail loudly via validation

  convert_kernel<<<2048, 256, 0, stream>>>(x, xb, M_ * DIM_);
  convert_kernel<<<1024, 256, 0, stream>>>(wq, wqb, DIM_ * DIM_);
  convert_kernel<<<1024, 256, 0, stream>>>(wk, wkb, DIM_ * DIM_);
  convert_kernel<<<1024, 256, 0, stream>>>(wv, wvb, DIM_ * DIM_);
  convert_kernel<<<1024, 256, 0, stream>>>(wo, wob, DIM_ * DIM_);
  rope_table_kernel<<<512, 256, 0, stream>>>(cosT, sinT);

  dim3 gq(DIM_ / 128, M_ / 128, 3);
  gemm_qkv_kernel<<<gq, 256, 0, stream>>>(xb, wqb, wkb, wvb, qb, kb, vb);

  rope_apply_kernel<<<(B_ * S_ * H_ * 64) / 256, 256, 0, stream>>>(qb, cosT, sinT);
  rope_apply_kernel<<<(B_ * S_ * H_ * 64) / 256, 256, 0, stream>>>(kb, cosT, sinT);

  dim3 ga(S_ / 128, H_, B_);
  attn_kernel<<<ga, 256, 0, stream>>>(qb, kb, vb, aob);

  dim3 go(DIM_ / 128, M_ / 128);
  gemm_out_kernel<<<go, 256, 0, stream>>>(aob, wob, (float*)d_out);
}

// Round 2
// 305.412 us; speedup vs baseline: 1.2426x; 1.2426x over previous
//
#include <hip/hip_runtime.h>
#include <cstdint>

typedef unsigned short u16;
typedef uint32_t u32;
typedef __attribute__((ext_vector_type(8))) short bf16x8;
typedef __attribute__((ext_vector_type(4))) float f32x4;
typedef __attribute__((ext_vector_type(16))) float f32x16;

#define DIM_ 2048
#define S_   2048
#define B_   2
#define H_   16
#define HD_  128
#define M_   (B_ * S_)  // 4096

// ---------- scalar bf16 helpers (RNE) ----------
__device__ __forceinline__ u16 f2b(float f) {
  union { float f; uint32_t u; } v; v.f = f;
  uint32_t u = v.u;
  return (u16)((u + 0x7FFFu + ((u >> 16) & 1u)) >> 16);
}
__device__ __forceinline__ float b2f(u16 h) {
  union { uint32_t u; float f; } v; v.u = ((uint32_t)h) << 16;
  return v.f;
}

// pack 2 f32 -> 2 bf16 in one u32 (lo = first arg)
__device__ __forceinline__ u32 cvtpk(float lo, float hi) {
  u32 r;
  asm("v_cvt_pk_bf16_f32 %0, %1, %2" : "=v"(r) : "v"(lo), "v"(hi));
  return r;
}

// ---------- global -> LDS async copy (16B per lane, wave-uniform LDS base) ----------
typedef __attribute__((address_space(3))) u16 lds_u16_t;
typedef __attribute__((address_space(1))) const u16 glob_u16_t;

__device__ __forceinline__ void gload16(const u16* g, u16* l) {
  __builtin_amdgcn_global_load_lds((glob_u16_t*)g, (lds_u16_t*)l, 16, 0, 0);
}

// ---------- fp32 -> bf16 convert ----------
__global__ void convert_kernel(const float* __restrict__ in, u16* __restrict__ out, int n) {
  int i = (blockIdx.x * blockDim.x + threadIdx.x) * 4;
  int stride = gridDim.x * blockDim.x * 4;
  for (; i < n; i += stride) {
    float4 v = *reinterpret_cast<const float4*>(in + i);
    uint64_t p = (uint64_t)f2b(v.x) | ((uint64_t)f2b(v.y) << 16) |
                 ((uint64_t)f2b(v.z) << 32) | ((uint64_t)f2b(v.w) << 48);
    *reinterpret_cast<uint64_t*>(out + i) = p;
  }
}

// ---------- RoPE tables: cos/sin [S][64] fp32 ----------
__global__ void rope_table_kernel(float* __restrict__ cosT, float* __restrict__ sinT) {
  int i = blockIdx.x * blockDim.x + threadIdx.x;
  if (i >= S_ * 64) return;
  int s = i >> 6, d = i & 63;
  float inv = powf(10000.0f, -(float)d * (1.0f / 64.0f));
  float ang = (float)s * inv;
  cosT[i] = cosf(ang);
  sinT[i] = sinf(ang);
}

// ---------- RoPE apply (in-place, rotate-half, D=128) ----------
__global__ void rope_apply_kernel(u16* __restrict__ buf, const float* __restrict__ cosT,
                                  const float* __restrict__ sinT) {
  int i = blockIdx.x * blockDim.x + threadIdx.x;  // over B*S*H*64
  if (i >= B_ * S_ * H_ * 64) return;
  int d = i & 63;
  int h = (i >> 6) & (H_ - 1);
  int row = i >> 10;        // b*S + s
  int s = row & (S_ - 1);
  u16* p = buf + (size_t)row * DIM_ + h * HD_ + d;
  float t1 = b2f(p[0]);
  float t2 = b2f(p[64]);
  float c = cosT[s * 64 + d];
  float sn = sinT[s * 64 + d];
  p[0]  = f2b(t1 * c - t2 * sn);
  p[64] = f2b(t2 * c + t1 * sn);
}

// ---------- GEMM: C[M,2048] = A[M,2048]bf16 @ W[2048,2048]^T bf16 ----------
template <bool OUTF32>
__device__ __forceinline__ void gemm_body(const u16* __restrict__ A, const u16* __restrict__ W,
                                          u16* __restrict__ Cb, float* __restrict__ Cf) {
  __shared__ __align__(16) u16 aT[128 * 32];
  __shared__ __align__(16) u16 bT[128 * 32];
  const int t = threadIdx.x;
  const int lane = t & 63;
  const int w = t >> 6;
  const int l15 = lane & 15;
  const int lg = lane >> 4;
  const int m0 = blockIdx.y * 128;
  const int n0 = blockIdx.x * 128;

  const f32x4 zero4 = {0.f, 0.f, 0.f, 0.f};
  f32x4 acc[2][8];
#pragma unroll
  for (int i = 0; i < 2; ++i)
#pragma unroll
    for (int j = 0; j < 8; ++j) acc[i][j] = zero4;

  for (int k0 = 0; k0 < DIM_; k0 += 32) {
    __syncthreads();
#pragma unroll
    for (int pass = 0; pass < 2; ++pass) {
      const int cb = pass * 256 + w * 64;
      const int cid = cb + lane;
      const int row = cid >> 2;
      const int col = (cid & 3) * 8;
      gload16(A + (size_t)(m0 + row) * DIM_ + k0 + col, aT + cb * 8);
      gload16(W + (size_t)(n0 + row) * DIM_ + k0 + col, bT + cb * 8);
    }
    __syncthreads();
    bf16x8 af[2], bf[8];
#pragma unroll
    for (int mi = 0; mi < 2; ++mi)
      af[mi] = *(const bf16x8*)(aT + (w * 32 + mi * 16 + l15) * 32 + lg * 8);
#pragma unroll
    for (int ni = 0; ni < 8; ++ni)
      bf[ni] = *(const bf16x8*)(bT + (ni * 16 + l15) * 32 + lg * 8);
#pragma unroll
    for (int mi = 0; mi < 2; ++mi)
#pragma unroll
      for (int ni = 0; ni < 8; ++ni)
        acc[mi][ni] =
            __builtin_amdgcn_mfma_f32_16x16x32_bf16(af[mi], bf[ni], acc[mi][ni], 0, 0, 0);
  }
#pragma unroll
  for (int mi = 0; mi < 2; ++mi)
#pragma unroll
    for (int ni = 0; ni < 8; ++ni) {
      const int row = m0 + w * 32 + mi * 16 + lg * 4;
      const int col = n0 + ni * 16 + l15;
#pragma unroll
      for (int r = 0; r < 4; ++r) {
        if (OUTF32)
          Cf[(size_t)(row + r) * DIM_ + col] = acc[mi][ni][r];
        else
          Cb[(size_t)(row + r) * DIM_ + col] = f2b(acc[mi][ni][r]);
      }
    }
}

__global__ __launch_bounds__(256, 2) void gemm_qkv_kernel(
    const u16* __restrict__ xb, const u16* __restrict__ wqb, const u16* __restrict__ wkb,
    const u16* __restrict__ wvb, u16* __restrict__ qb, u16* __restrict__ kb,
    u16* __restrict__ vb) {
  const u16* W;
  u16* O;
  if (blockIdx.z == 0) { W = wqb; O = qb; }
  else if (blockIdx.z == 1) { W = wkb; O = kb; }
  else { W = wvb; O = vb; }
  gemm_body<false>(xb, W, O, nullptr);
}

__global__ __launch_bounds__(256, 2) void gemm_out_kernel(const u16* __restrict__ A,
                                                          const u16* __restrict__ W,
                                                          float* __restrict__ C) {
  gemm_body<true>(A, W, nullptr, C);
}

// ---------- causal flash attention, swapped-QK^T 32x32 structure ----------
// block = 256 thr = 4 waves; each wave owns 32 q-rows (QBLK=128/block); KV tiles of 64.
// S^T = mfma(A=K, B=Q^T): lane owns q-col = lane&31; softmax fully in-register.
// PV: O^T = mfma(A=V^T, B=P^T): col = q = lane&31 -> per-lane rescale/normalize.
#define CEXP 0.12751744f  /* (1/sqrt(128)) * log2(e) */

__global__ __launch_bounds__(256, 2) void attn_kernel(const u16* __restrict__ q,
                                                      const u16* __restrict__ k,
                                                      const u16* __restrict__ v,
                                                      u16* __restrict__ ao) {
  // kTl [64][128] (K, chunk-XOR-swizzled) | vTl [128][64] (V^T, swizzled)
  // epilogue reuses whole smem as per-wave [32][136] O transpose buffers.
  __shared__ __align__(16) u16 smem[17408];
  u16* kTl = smem;
  u16* vTl = smem + 8192;

  // pair reversed qt across b so the two resident blocks per CU sum to const work
  const int qt   = blockIdx.z ? (int)blockIdx.x : (int)(gridDim.x - 1 - blockIdx.x);
  const int head = blockIdx.y;
  const int b    = blockIdx.z;
  const int t = threadIdx.x;
  const int lane = t & 63;
  const int w = t >> 6;
  const int l31 = lane & 31;
  const int hi = lane >> 5;
  const int kxor = (lane & 7) << 3;   // chunk swizzle term (row&7 == lane&7 for our rows)
  const int qrow0 = qt * 128 + w * 32;
  const size_t bS = (size_t)b * S_;

  // Q fragments (B-operand): lane holds Q[q=l31][d = st*16 + hi*8 + j]
  bf16x8 qf[8];
  {
    const u16* qrow = q + (bS + qrow0 + l31) * DIM_ + head * HD_;
#pragma unroll
    for (int st = 0; st < 8; ++st)
      qf[st] = *(const bf16x8*)(qrow + st * 16 + hi * 8);
  }

  f32x16 accO[4];
#pragma unroll
  for (int db = 0; db < 4; ++db)
#pragma unroll
    for (int r = 0; r < 16; ++r) accO[db][r] = 0.f;
  float m = -1e30f, l = 0.f;

  const int tmax_w = 2 * qt + (w >> 1);  // waves 0,1 finish one tile earlier
  const int ttend = 2 * qt + 1;

  for (int tt = 0; tt <= ttend; ++tt) {
    __syncthreads();  // previous tile's LDS reads done before overwrite

    // --- stage V: global->reg (lane=k row), then transposed+swizzled LDS writes ---
    bf16x8 vv[4];
#pragma unroll
    for (int p = 0; p < 4; ++p) {
      const int dchunk = p * 4 + w;  // wave-uniform
      vv[p] = *(const bf16x8*)(v + (bS + tt * 64 + lane) * DIM_ + head * HD_ + dchunk * 8);
    }
    // --- stage K via global_load_lds, inverse-swizzled global source (rule 21) ---
#pragma unroll
    for (int p = 0; p < 4; ++p) {
      const int cb = p * 256 + w * 64;      // wave-uniform chunk base
      const int cid = cb + lane;
      const int kr = cid >> 4;              // k-row 0..63
      const int cg = (cid & 15) ^ (kr & 7); // source chunk within row
      gload16(k + (bS + tt * 64 + kr) * DIM_ + head * HD_ + cg * 8, kTl + cb * 8);
    }
#pragma unroll
    for (int p = 0; p < 4; ++p) {
      const int dchunk = p * 4 + w;
#pragma unroll
      for (int j = 0; j < 8; ++j) {
        const int d = dchunk * 8 + j;
        vTl[d * 64 + (lane ^ ((d & 7) << 3))] = (u16)vv[p][j];
      }
    }
    __syncthreads();  // drains gload_lds + ds writes

    if (tt <= tmax_w) {
      // ---- S^T = K . Q^T  (lane: col q=l31; rows k via regs) ----
      f32x16 sA, sB;
#pragma unroll
      for (int r = 0; r < 16; ++r) { sA[r] = 0.f; sB[r] = 0.f; }
#pragma unroll
      for (int st = 0; st < 8; ++st) {
        const int dc = st * 16 + hi * 8;
        bf16x8 k0 = *(const bf16x8*)(kTl + l31 * 128 + (dc ^ kxor));
        bf16x8 k1 = *(const bf16x8*)(kTl + (32 + l31) * 128 + (dc ^ kxor));
        sA = __builtin_amdgcn_mfma_f32_32x32x16_bf16(k0, qf[st], sA, 0, 0, 0);
        sB = __builtin_amdgcn_mfma_f32_32x32x16_bf16(k1, qf[st], sB, 0, 0, 0);
      }

      const int qg = qrow0 + l31;
      if (tt * 64 + 63 > qrow0) {  // wave-uniform: only diagonal tiles mask
        const int kb = tt * 64 + 4 * hi;
#pragma unroll
        for (int r = 0; r < 16; ++r) {
          const int kg = kb + (r & 3) + 8 * (r >> 2);
          sA[r] = (kg <= qg) ? sA[r] : -1e30f;
          sB[r] = (kg + 32 <= qg) ? sB[r] : -1e30f;
        }
      }

      // ---- online softmax, in-register (raw units; scale folded into exp2) ----
      float pm = sA[0];
#pragma unroll
      for (int r = 1; r < 16; ++r) pm = fmaxf(pm, sA[r]);
#pragma unroll
      for (int r = 0; r < 16; ++r) pm = fmaxf(pm, sB[r]);
      pm = fmaxf(pm, __shfl_xor(pm, 32));
      const float mN = fmaxf(m, pm);
      if (!__all(pm - m <= 90.5f)) {  // T13 defer-max, THR=8 nat units
        const float osc = exp2f((m - mN) * CEXP);
        l *= osc;
#pragma unroll
        for (int db = 0; db < 4; ++db)
#pragma unroll
          for (int r = 0; r < 16; ++r) accO[db][r] *= osc;
        m = mN;
      }
      const float mc = m * CEXP;
      float ls = 0.f;
#pragma unroll
      for (int r = 0; r < 16; ++r) {
        const float pa = exp2f(__builtin_fmaf(sA[r], CEXP, -mc));
        const float pb = exp2f(__builtin_fmaf(sB[r], CEXP, -mc));
        sA[r] = pa; sB[r] = pb;
        ls += pa + pb;
      }
      ls += __shfl_xor(ls, 32);
      l += ls;

      // ---- P->bf16 (cvt_pk + permlane32_swap, T12) and PV: O^T += V^T . P^T ----
#define PV_STEP(ARR, R0, ST2)                                                      \
      {                                                                            \
        u32 a0 = cvtpk(ARR[(R0) + 0], ARR[(R0) + 1]);                              \
        u32 a1 = cvtpk(ARR[(R0) + 2], ARR[(R0) + 3]);                              \
        u32 b0 = cvtpk(ARR[(R0) + 4], ARR[(R0) + 5]);                              \
        u32 b1 = cvtpk(ARR[(R0) + 6], ARR[(R0) + 7]);                              \
        asm("v_permlane32_swap_b32 %0, %1" : "+v"(a0), "+v"(b0));                  \
        asm("v_permlane32_swap_b32 %0, %1" : "+v"(a1), "+v"(b1));                  \
        union { u32 uu[4]; bf16x8 v8; } pf;                                        \
        pf.uu[0] = a0; pf.uu[1] = a1; pf.uu[2] = b0; pf.uu[3] = b1;                \
        const int ko = (ST2) * 16 + hi * 8;                                        \
        _Pragma("unroll")                                                          \
        for (int db = 0; db < 4; ++db) {                                           \
          const int dr = db * 32 + l31;                                            \
          bf16x8 vf = *(const bf16x8*)(vTl + dr * 64 + (ko ^ kxor));               \
          accO[db] =                                                               \
              __builtin_amdgcn_mfma_f32_32x32x16_bf16(vf, pf.v8, accO[db], 0, 0, 0); \
        }                                                                          \
      }
      PV_STEP(sA, 0, 0)
      PV_STEP(sA, 8, 1)
      PV_STEP(sB, 0, 2)
      PV_STEP(sB, 8, 3)
#undef PV_STEP
    }
  }

  // ---- epilogue: normalize, transpose O^T->O through LDS, coalesced store ----
  __syncthreads();  // all tiles done; smem reused as oT
  const float linv = 1.0f / l;
  u16* oT = smem + w * 4352;  // per-wave [32 q][136 d]
#pragma unroll
  for (int db = 0; db < 4; ++db)
#pragma unroll
    for (int q4 = 0; q4 < 4; ++q4) {
      const int dbase = db * 32 + q4 * 8 + hi * 4;
      const u32 lo = cvtpk(accO[db][q4 * 4 + 0] * linv, accO[db][q4 * 4 + 1] * linv);
      const u32 hiw = cvtpk(accO[db][q4 * 4 + 2] * linv, accO[db][q4 * 4 + 3] * linv);
      *(u32*)(oT + l31 * 136 + dbase) = lo;
      *(u32*)(oT + l31 * 136 + dbase + 2) = hiw;
    }
  __syncthreads();
#pragma unroll
  for (int i = 0; i < 8; ++i) {
    const int cid = i * 64 + lane;
    const int qloc = cid >> 4;
    const int c = cid & 15;
    const bf16x8 val = *(const bf16x8*)(oT + qloc * 136 + c * 8);
    *(bf16x8*)(ao + (bS + qrow0 - w * 32 + w * 32 + qloc) * DIM_ + head * HD_ + c * 8) = val;
  }
}

// ---------- launch ----------
extern "C" void kernel_launch(void* const* d_in, const int* in_sizes, int n_in,
                              void* d_out, int out_size, void* d_ws, size_t ws_size,
                              hipStream_t stream) {
  const float* x  = (const float*)d_in[0];
  const float* wq = (const float*)d_in[2];
  const float* wk = (const float*)d_in[3];
  const float* wv = (const float*)d_in[4];
  const float* wo = (const float*)d_in[5];

  char* ws = (char*)d_ws;
  size_t off = 0;
  auto carve = [&](size_t bytes) { char* p = ws + off; off += bytes; return p; };
  u16* xb   = (u16*)carve((size_t)M_ * DIM_ * 2);
  u16* wqb  = (u16*)carve((size_t)DIM_ * DIM_ * 2);
  u16* wkb  = (u16*)carve((size_t)DIM_ * DIM_ * 2);
  u16* wvb  = (u16*)carve((size_t)DIM_ * DIM_ * 2);
  u16* wob  = (u16*)carve((size_t)DIM_ * DIM_ * 2);
  u16* qb   = (u16*)carve((size_t)M_ * DIM_ * 2);
  u16* kb   = (u16*)carve((size_t)M_ * DIM_ * 2);
  u16* vb   = (u16*)carve((size_t)M_ * DIM_ * 2);
  u16* aob  = (u16*)carve((size_t)M_ * DIM_ * 2);
  float* cosT = (float*)carve((size_t)S_ * 64 * 4);
  float* sinT = (float*)carve((size_t)S_ * 64 * 4);
  if (off > ws_size) return;

  convert_kernel<<<2048, 256, 0, stream>>>(x, xb, M_ * DIM_);
  convert_kernel<<<1024, 256, 0, stream>>>(wq, wqb, DIM_ * DIM_);
  convert_kernel<<<1024, 256, 0, stream>>>(wk, wkb, DIM_ * DIM_);
  convert_kernel<<<1024, 256, 0, stream>>>(wv, wvb, DIM_ * DIM_);
  convert_kernel<<<1024, 256, 0, stream>>>(wo, wob, DIM_ * DIM_);
  rope_table_kernel<<<512, 256, 0, stream>>>(cosT, sinT);

  dim3 gq(DIM_ / 128, M_ / 128, 3);
  gemm_qkv_kernel<<<gq, 256, 0, stream>>>(xb, wqb, wkb, wvb, qb, kb, vb);

  rope_apply_kernel<<<(B_ * S_ * H_ * 64) / 256, 256, 0, stream>>>(qb, cosT, sinT);
  rope_apply_kernel<<<(B_ * S_ * H_ * 64) / 256, 256, 0, stream>>>(kb, cosT, sinT);

  dim3 ga(S_ / 128, H_, B_);
  attn_kernel<<<ga, 256, 0, stream>>>(qb, kb, vb, aob);

  dim3 go(DIM_ / 128, M_ / 128);
  gemm_out_kernel<<<go, 256, 0, stream>>>(aob, wob, (float*)d_out);
}

// Round 3
// 294.528 us; speedup vs baseline: 1.2885x; 1.0370x over previous
//
#include <hip/hip_runtime.h>
#include <cstdint>

typedef unsigned short u16;
typedef uint32_t u32;
typedef __attribute__((ext_vector_type(8))) short bf16x8;
typedef __attribute__((ext_vector_type(4))) float f32x4;
typedef __attribute__((ext_vector_type(16))) float f32x16;

#define DIM_ 2048
#define S_   2048
#define B_   2
#define H_   16
#define HD_  128
#define M_   (B_ * S_)  // 4096

// ---------- scalar bf16 helpers (RNE) ----------
__device__ __forceinline__ u16 f2b(float f) {
  union { float f; uint32_t u; } v; v.f = f;
  uint32_t u = v.u;
  return (u16)((u + 0x7FFFu + ((u >> 16) & 1u)) >> 16);
}
__device__ __forceinline__ float b2f(u16 h) {
  union { uint32_t u; float f; } v; v.u = ((uint32_t)h) << 16;
  return v.f;
}

// pack 2 f32 -> 2 bf16 in one u32 (lo = first arg)
__device__ __forceinline__ u32 cvtpk(float lo, float hi) {
  u32 r;
  asm("v_cvt_pk_bf16_f32 %0, %1, %2" : "=v"(r) : "v"(lo), "v"(hi));
  return r;
}

// ---------- global -> LDS async copy (16B per lane, wave-uniform LDS base) ----------
typedef __attribute__((address_space(3))) u16 lds_u16_t;
typedef __attribute__((address_space(1))) const u16 glob_u16_t;

__device__ __forceinline__ void gload16(const u16* g, u16* l) {
  __builtin_amdgcn_global_load_lds((glob_u16_t*)g, (lds_u16_t*)l, 16, 0, 0);
}

// ---------- fp32 -> bf16 convert ----------
__global__ void convert_kernel(const float* __restrict__ in, u16* __restrict__ out, int n) {
  int i = (blockIdx.x * blockDim.x + threadIdx.x) * 4;
  int stride = gridDim.x * blockDim.x * 4;
  for (; i < n; i += stride) {
    float4 v = *reinterpret_cast<const float4*>(in + i);
    uint64_t p = (uint64_t)f2b(v.x) | ((uint64_t)f2b(v.y) << 16) |
                 ((uint64_t)f2b(v.z) << 32) | ((uint64_t)f2b(v.w) << 48);
    *reinterpret_cast<uint64_t*>(out + i) = p;
  }
}

// ---------- RoPE tables: cos/sin [S][64] fp32 ----------
__global__ void rope_table_kernel(float* __restrict__ cosT, float* __restrict__ sinT) {
  int i = blockIdx.x * blockDim.x + threadIdx.x;
  if (i >= S_ * 64) return;
  int s = i >> 6, d = i & 63;
  float inv = powf(10000.0f, -(float)d * (1.0f / 64.0f));
  float ang = (float)s * inv;
  cosT[i] = cosf(ang);
  sinT[i] = sinf(ang);
}

// ---------- RoPE apply (in-place, rotate-half, D=128) ----------
__global__ void rope_apply_kernel(u16* __restrict__ buf, const float* __restrict__ cosT,
                                  const float* __restrict__ sinT) {
  int i = blockIdx.x * blockDim.x + threadIdx.x;  // over B*S*H*64
  if (i >= B_ * S_ * H_ * 64) return;
  int d = i & 63;
  int h = (i >> 6) & (H_ - 1);
  int row = i >> 10;        // b*S + s
  int s = row & (S_ - 1);
  u16* p = buf + (size_t)row * DIM_ + h * HD_ + d;
  float t1 = b2f(p[0]);
  float t2 = b2f(p[64]);
  float c = cosT[s * 64 + d];
  float sn = sinT[s * 64 + d];
  p[0]  = f2b(t1 * c - t2 * sn);
  p[64] = f2b(t2 * c + t1 * sn);
}

// ==================================================================================
// 8-phase 256x256 GEMM (T2+T3+T4+T5), QKV fused: C[4096,2048] = A @ W^T for 3 W's.
// 512 thr = 8 waves (2M x 4N); wave tile 128x64; BK=64; LDS 128KB (2 dbuf x A,B).
// Per K-tile 4 phases (quadrants zigzag (0,0)->(1,0)->(1,1)->(0,1)); 16 MFMA/phase.
// Stage schedule (race-free by barrier ordering, slot last-read -> restage issue):
//   P0: stage B1(t+1)->buf^1 | P1: A0(t+2)->cur | P2: B0(t+2)->cur | P3: A1(t+2)->cur
// vmcnt(6) at end of each tile (3 half-tiles = 6 loads in flight); vmcnt(0) at NT-2.
// LDS chunk-XOR swizzle (chunk ^= row&7): frag ds_read_b128 = 2 lanes/bank (free).
// ==================================================================================
#define G8_NT 32  // 2048 / 64

__global__ __launch_bounds__(512, 2) void gemm8_qkv_kernel(
    const u16* __restrict__ xb, const u16* __restrict__ wqb, const u16* __restrict__ wkb,
    const u16* __restrict__ wvb, u16* __restrict__ qb, u16* __restrict__ kb,
    u16* __restrict__ vb) {
  __shared__ __align__(16) u16 lds[65536];  // [buf2][mat2][256*64] = 128 KB

  // XCD swizzle (384 % 8 == 0) + A-panel grouping: logical = mt*24 + z*8 + nt
  const int bid = blockIdx.x;
  const int logical = (bid & 7) * 48 + (bid >> 3);
  const int mt = logical / 24;
  const int rem = logical % 24;
  const int z = rem >> 3;
  const int nt = rem & 7;
  const u16* Wsrc = (z == 0) ? wqb : (z == 1) ? wkb : wvb;
  u16* out = (z == 0) ? qb : (z == 1) ? kb : vb;

  const int tid = threadIdx.x;
  const int lane = tid & 63;
  const int w = tid >> 6;
  const int wm = w >> 2, wn = w & 3;
  const int l15 = lane & 15, lg = lane >> 4;

  const u16* Abase = xb + (size_t)(mt * 256) * DIM_;
  const u16* Bbase = Wsrc + (size_t)(nt * 256) * DIM_;

  f32x4 acc[8][4];
#pragma unroll
  for (int i = 0; i < 8; ++i)
#pragma unroll
    for (int j = 0; j < 4; ++j) acc[i][j] = (f32x4){0.f, 0.f, 0.f, 0.f};

  // stage one half-tile (128 rows x 64 cols) = 2 gload16/thread, linear LDS dest,
  // inverse-swizzled global source (rule 21)
  auto stageH = [&](int buf, int mat, int half, int kt) {
    const u16* src = (mat ? Bbase : Abase) + (size_t)(half * 128) * DIM_ + kt * 64;
    u16* dstTile = lds + buf * 32768 + mat * 16384 + half * 8192;
#pragma unroll
    for (int sweep = 0; sweep < 2; ++sweep) {
      const int cb = sweep * 512 + (w << 6);  // wave-uniform chunk base
      const int i = cb + lane;
      const int r = i >> 3;
      const int c = (i & 7) ^ (r & 7);  // logical chunk for stored slot
      gload16(src + (size_t)r * DIM_ + c * 8, dstTile + cb * 8);
    }
  };
  auto rdA = [&](int buf, int mh, int mi, int ks) -> bf16x8 {
    const int row = wm * 128 + mh * 64 + mi * 16 + l15;
    const int chunk = ((ks << 2) + lg) ^ (l15 & 7);
    return *(const bf16x8*)(lds + buf * 32768 + row * 64 + chunk * 8);
  };
  auto rdB = [&](int buf, int nh, int ni, int ks) -> bf16x8 {
    const int row = wn * 64 + nh * 32 + ni * 16 + l15;
    const int chunk = ((ks << 2) + lg) ^ (l15 & 7);
    return *(const bf16x8*)(lds + buf * 32768 + 16384 + row * 64 + chunk * 8);
  };

  // ---- prologue: tile0 complete + tile1 A0,B0,A1 (FIFO order matters) ----
  stageH(0, 0, 0, 0);
  stageH(0, 1, 0, 0);
  stageH(0, 0, 1, 0);
  stageH(0, 1, 1, 0);
  stageH(1, 0, 0, 1);
  stageH(1, 1, 0, 1);
  stageH(1, 0, 1, 1);
  __builtin_amdgcn_sched_barrier(0);
  asm volatile("s_waitcnt vmcnt(6)" ::: "memory");  // tile0's 8 loads landed
  __builtin_amdgcn_sched_barrier(0);
  __builtin_amdgcn_s_barrier();

  bf16x8 a0[8], a1[8], bb[4];

  for (int t = 0; t < G8_NT; ++t) {
    const int cur = t & 1;

    // ---------- P0: quad(0,0) — read A0(8)+B0(4); stage B1(t+1)->buf^1 ----------
#pragma unroll
    for (int mi = 0; mi < 4; ++mi)
#pragma unroll
      for (int ks = 0; ks < 2; ++ks) a0[mi * 2 + ks] = rdA(cur, 0, mi, ks);
#pragma unroll
    for (int ni = 0; ni < 2; ++ni)
#pragma unroll
      for (int ks = 0; ks < 2; ++ks) bb[ni * 2 + ks] = rdB(cur, 0, ni, ks);
    if (t + 1 < G8_NT) stageH(cur ^ 1, 1, 1, t + 1);
    __builtin_amdgcn_s_barrier();
    asm volatile("s_waitcnt lgkmcnt(0)" ::: "memory");
    __builtin_amdgcn_sched_barrier(0);
    __builtin_amdgcn_s_setprio(1);
#pragma unroll
    for (int mi = 0; mi < 4; ++mi)
#pragma unroll
      for (int ni = 0; ni < 2; ++ni)
#pragma unroll
        for (int ks = 0; ks < 2; ++ks)
          acc[mi][ni] =
              __builtin_amdgcn_mfma_f32_16x16x32_bf16(a0[mi * 2 + ks], bb[ni * 2 + ks],
                                                      acc[mi][ni], 0, 0, 0);
    __builtin_amdgcn_s_setprio(0);
    __builtin_amdgcn_s_barrier();

    // ---------- P1: quad(1,0) — read A1(8), reuse B0; stage A0(t+2)->cur ----------
#pragma unroll
    for (int mi = 0; mi < 4; ++mi)
#pragma unroll
      for (int ks = 0; ks < 2; ++ks) a1[mi * 2 + ks] = rdA(cur, 1, mi, ks);
    if (t + 2 < G8_NT) stageH(cur, 0, 0, t + 2);
    __builtin_amdgcn_s_barrier();
    asm volatile("s_waitcnt lgkmcnt(0)" ::: "memory");
    __builtin_amdgcn_sched_barrier(0);
    __builtin_amdgcn_s_setprio(1);
#pragma unroll
    for (int mi = 0; mi < 4; ++mi)
#pragma unroll
      for (int ni = 0; ni < 2; ++ni)
#pragma unroll
        for (int ks = 0; ks < 2; ++ks)
          acc[4 + mi][ni] =
              __builtin_amdgcn_mfma_f32_16x16x32_bf16(a1[mi * 2 + ks], bb[ni * 2 + ks],
                                                      acc[4 + mi][ni], 0, 0, 0);
    __builtin_amdgcn_s_setprio(0);
    __builtin_amdgcn_s_barrier();

    // ---------- P2: quad(1,1) — read B1(4), reuse A1; stage B0(t+2)->cur ----------
#pragma unroll
    for (int ni = 0; ni < 2; ++ni)
#pragma unroll
      for (int ks = 0; ks < 2; ++ks) bb[ni * 2 + ks] = rdB(cur, 1, ni, ks);
    if (t + 2 < G8_NT) stageH(cur, 1, 0, t + 2);
    __builtin_amdgcn_s_barrier();
    asm volatile("s_waitcnt lgkmcnt(0)" ::: "memory");
    __builtin_amdgcn_sched_barrier(0);
    __builtin_amdgcn_s_setprio(1);
#pragma unroll
    for (int mi = 0; mi < 4; ++mi)
#pragma unroll
      for (int ni = 0; ni < 2; ++ni)
#pragma unroll
        for (int ks = 0; ks < 2; ++ks)
          acc[4 + mi][2 + ni] =
              __builtin_amdgcn_mfma_f32_16x16x32_bf16(a1[mi * 2 + ks], bb[ni * 2 + ks],
                                                      acc[4 + mi][2 + ni], 0, 0, 0);
    __builtin_amdgcn_s_setprio(0);
    __builtin_amdgcn_s_barrier();

    // ---------- P3: quad(0,1) — no reads (reuse A0,B1); stage A1(t+2)->cur; vmcnt ----------
    if (t + 2 < G8_NT) stageH(cur, 0, 1, t + 2);
    __builtin_amdgcn_s_barrier();
    __builtin_amdgcn_s_setprio(1);
#pragma unroll
    for (int mi = 0; mi < 4; ++mi)
#pragma unroll
      for (int ni = 0; ni < 2; ++ni)
#pragma unroll
        for (int ks = 0; ks < 2; ++ks)
          acc[mi][2 + ni] =
              __builtin_amdgcn_mfma_f32_16x16x32_bf16(a0[mi * 2 + ks], bb[ni * 2 + ks],
                                                      acc[mi][2 + ni], 0, 0, 0);
    __builtin_amdgcn_s_setprio(0);
    if (t < G8_NT - 2) {
      __builtin_amdgcn_sched_barrier(0);
      asm volatile("s_waitcnt vmcnt(6)" ::: "memory");  // tile t+1 fully landed
      __builtin_amdgcn_sched_barrier(0);
    } else if (t == G8_NT - 2) {
      __builtin_amdgcn_sched_barrier(0);
      asm volatile("s_waitcnt vmcnt(0)" ::: "memory");  // drain for final tile
      __builtin_amdgcn_sched_barrier(0);
    }
    __builtin_amdgcn_s_barrier();
  }

  // ---- epilogue: bf16 store, D layout row=(lane>>4)*4+r, col=lane&15 ----
#pragma unroll
  for (int mi = 0; mi < 8; ++mi)
#pragma unroll
    for (int ni = 0; ni < 4; ++ni) {
      const int row = mt * 256 + wm * 128 + mi * 16 + lg * 4;
      const int col = nt * 256 + wn * 64 + ni * 16 + l15;
#pragma unroll
      for (int r = 0; r < 4; ++r)
        out[(size_t)(row + r) * DIM_ + col] = f2b(acc[mi][ni][r]);
    }
}

// ---------- 128x128 GEMM (m97 structure) — kept for O-projection ----------
template <bool OUTF32>
__device__ __forceinline__ void gemm_body(const u16* __restrict__ A, const u16* __restrict__ W,
                                          u16* __restrict__ Cb, float* __restrict__ Cf) {
  __shared__ __align__(16) u16 aT[128 * 32];
  __shared__ __align__(16) u16 bT[128 * 32];
  const int t = threadIdx.x;
  const int lane = t & 63;
  const int w = t >> 6;
  const int l15 = lane & 15;
  const int lg = lane >> 4;
  const int m0 = blockIdx.y * 128;
  const int n0 = blockIdx.x * 128;

  const f32x4 zero4 = {0.f, 0.f, 0.f, 0.f};
  f32x4 acc[2][8];
#pragma unroll
  for (int i = 0; i < 2; ++i)
#pragma unroll
    for (int j = 0; j < 8; ++j) acc[i][j] = zero4;

  for (int k0 = 0; k0 < DIM_; k0 += 32) {
    __syncthreads();
#pragma unroll
    for (int pass = 0; pass < 2; ++pass) {
      const int cb = pass * 256 + w * 64;
      const int cid = cb + lane;
      const int row = cid >> 2;
      const int col = (cid & 3) * 8;
      gload16(A + (size_t)(m0 + row) * DIM_ + k0 + col, aT + cb * 8);
      gload16(W + (size_t)(n0 + row) * DIM_ + k0 + col, bT + cb * 8);
    }
    __syncthreads();
    bf16x8 af[2], bf[8];
#pragma unroll
    for (int mi = 0; mi < 2; ++mi)
      af[mi] = *(const bf16x8*)(aT + (w * 32 + mi * 16 + l15) * 32 + lg * 8);
#pragma unroll
    for (int ni = 0; ni < 8; ++ni)
      bf[ni] = *(const bf16x8*)(bT + (ni * 16 + l15) * 32 + lg * 8);
#pragma unroll
    for (int mi = 0; mi < 2; ++mi)
#pragma unroll
      for (int ni = 0; ni < 8; ++ni)
        acc[mi][ni] =
            __builtin_amdgcn_mfma_f32_16x16x32_bf16(af[mi], bf[ni], acc[mi][ni], 0, 0, 0);
  }
#pragma unroll
  for (int mi = 0; mi < 2; ++mi)
#pragma unroll
    for (int ni = 0; ni < 8; ++ni) {
      const int row = m0 + w * 32 + mi * 16 + lg * 4;
      const int col = n0 + ni * 16 + l15;
#pragma unroll
      for (int r = 0; r < 4; ++r) {
        if (OUTF32)
          Cf[(size_t)(row + r) * DIM_ + col] = acc[mi][ni][r];
        else
          Cb[(size_t)(row + r) * DIM_ + col] = f2b(acc[mi][ni][r]);
      }
    }
}

__global__ __launch_bounds__(256, 2) void gemm_out_kernel(const u16* __restrict__ A,
                                                          const u16* __restrict__ W,
                                                          float* __restrict__ C) {
  gemm_body<true>(A, W, nullptr, C);
}

// ---------- causal flash attention, swapped-QK^T 32x32 structure ----------
#define CEXP 0.12751744f  /* (1/sqrt(128)) * log2(e) */

__global__ __launch_bounds__(256, 2) void attn_kernel(const u16* __restrict__ q,
                                                      const u16* __restrict__ k,
                                                      const u16* __restrict__ v,
                                                      u16* __restrict__ ao) {
  __shared__ __align__(16) u16 smem[17408];
  u16* kTl = smem;
  u16* vTl = smem + 8192;

  const int qt   = blockIdx.z ? (int)blockIdx.x : (int)(gridDim.x - 1 - blockIdx.x);
  const int head = blockIdx.y;
  const int b    = blockIdx.z;
  const int t = threadIdx.x;
  const int lane = t & 63;
  const int w = t >> 6;
  const int l31 = lane & 31;
  const int hi = lane >> 5;
  const int kxor = (lane & 7) << 3;
  const int qrow0 = qt * 128 + w * 32;
  const size_t bS = (size_t)b * S_;

  bf16x8 qf[8];
  {
    const u16* qrow = q + (bS + qrow0 + l31) * DIM_ + head * HD_;
#pragma unroll
    for (int st = 0; st < 8; ++st)
      qf[st] = *(const bf16x8*)(qrow + st * 16 + hi * 8);
  }

  f32x16 accO[4];
#pragma unroll
  for (int db = 0; db < 4; ++db)
#pragma unroll
    for (int r = 0; r < 16; ++r) accO[db][r] = 0.f;
  float m = -1e30f, l = 0.f;

  const int tmax_w = 2 * qt + (w >> 1);
  const int ttend = 2 * qt + 1;

  for (int tt = 0; tt <= ttend; ++tt) {
    __syncthreads();

    bf16x8 vv[4];
#pragma unroll
    for (int p = 0; p < 4; ++p) {
      const int dchunk = p * 4 + w;
      vv[p] = *(const bf16x8*)(v + (bS + tt * 64 + lane) * DIM_ + head * HD_ + dchunk * 8);
    }
#pragma unroll
    for (int p = 0; p < 4; ++p) {
      const int cb = p * 256 + w * 64;
      const int cid = cb + lane;
      const int kr = cid >> 4;
      const int cg = (cid & 15) ^ (kr & 7);
      gload16(k + (bS + tt * 64 + kr) * DIM_ + head * HD_ + cg * 8, kTl + cb * 8);
    }
#pragma unroll
    for (int p = 0; p < 4; ++p) {
      const int dchunk = p * 4 + w;
#pragma unroll
      for (int j = 0; j < 8; ++j) {
        const int d = dchunk * 8 + j;
        vTl[d * 64 + (lane ^ ((d & 7) << 3))] = (u16)vv[p][j];
      }
    }
    __syncthreads();

    if (tt <= tmax_w) {
      f32x16 sA, sB;
#pragma unroll
      for (int r = 0; r < 16; ++r) { sA[r] = 0.f; sB[r] = 0.f; }
#pragma unroll
      for (int st = 0; st < 8; ++st) {
        const int dc = st * 16 + hi * 8;
        bf16x8 k0 = *(const bf16x8*)(kTl + l31 * 128 + (dc ^ kxor));
        bf16x8 k1 = *(const bf16x8*)(kTl + (32 + l31) * 128 + (dc ^ kxor));
        sA = __builtin_amdgcn_mfma_f32_32x32x16_bf16(k0, qf[st], sA, 0, 0, 0);
        sB = __builtin_amdgcn_mfma_f32_32x32x16_bf16(k1, qf[st], sB, 0, 0, 0);
      }

      const int qg = qrow0 + l31;
      if (tt * 64 + 63 > qrow0) {
        const int kb = tt * 64 + 4 * hi;
#pragma unroll
        for (int r = 0; r < 16; ++r) {
          const int kg = kb + (r & 3) + 8 * (r >> 2);
          sA[r] = (kg <= qg) ? sA[r] : -1e30f;
          sB[r] = (kg + 32 <= qg) ? sB[r] : -1e30f;
        }
      }

      float pm = sA[0];
#pragma unroll
      for (int r = 1; r < 16; ++r) pm = fmaxf(pm, sA[r]);
#pragma unroll
      for (int r = 0; r < 16; ++r) pm = fmaxf(pm, sB[r]);
      pm = fmaxf(pm, __shfl_xor(pm, 32));
      const float mN = fmaxf(m, pm);
      if (!__all(pm - m <= 90.5f)) {
        const float osc = exp2f((m - mN) * CEXP);
        l *= osc;
#pragma unroll
        for (int db = 0; db < 4; ++db)
#pragma unroll
          for (int r = 0; r < 16; ++r) accO[db][r] *= osc;
        m = mN;
      }
      const float mc = m * CEXP;
      float ls = 0.f;
#pragma unroll
      for (int r = 0; r < 16; ++r) {
        const float pa = exp2f(__builtin_fmaf(sA[r], CEXP, -mc));
        const float pb = exp2f(__builtin_fmaf(sB[r], CEXP, -mc));
        sA[r] = pa; sB[r] = pb;
        ls += pa + pb;
      }
      ls += __shfl_xor(ls, 32);
      l += ls;

#define PV_STEP(ARR, R0, ST2)                                                      \
      {                                                                            \
        u32 a0 = cvtpk(ARR[(R0) + 0], ARR[(R0) + 1]);                              \
        u32 a1 = cvtpk(ARR[(R0) + 2], ARR[(R0) + 3]);                              \
        u32 b0 = cvtpk(ARR[(R0) + 4], ARR[(R0) + 5]);                              \
        u32 b1 = cvtpk(ARR[(R0) + 6], ARR[(R0) + 7]);                              \
        asm("v_permlane32_swap_b32 %0, %1" : "+v"(a0), "+v"(b0));                  \
        asm("v_permlane32_swap_b32 %0, %1" : "+v"(a1), "+v"(b1));                  \
        union { u32 uu[4]; bf16x8 v8; } pf;                                        \
        pf.uu[0] = a0; pf.uu[1] = a1; pf.uu[2] = b0; pf.uu[3] = b1;                \
        const int ko = (ST2) * 16 + hi * 8;                                        \
        _Pragma("unroll")                                                          \
        for (int db = 0; db < 4; ++db) {                                           \
          const int dr = db * 32 + l31;                                            \
          bf16x8 vf = *(const bf16x8*)(vTl + dr * 64 + (ko ^ kxor));               \
          accO[db] =                                                               \
              __builtin_amdgcn_mfma_f32_32x32x16_bf16(vf, pf.v8, accO[db], 0, 0, 0); \
        }                                                                          \
      }
      PV_STEP(sA, 0, 0)
      PV_STEP(sA, 8, 1)
      PV_STEP(sB, 0, 2)
      PV_STEP(sB, 8, 3)
#undef PV_STEP
    }
  }

  __syncthreads();
  const float linv = 1.0f / l;
  u16* oT = smem + w * 4352;
#pragma unroll
  for (int db = 0; db < 4; ++db)
#pragma unroll
    for (int q4 = 0; q4 < 4; ++q4) {
      const int dbase = db * 32 + q4 * 8 + hi * 4;
      const u32 lo = cvtpk(accO[db][q4 * 4 + 0] * linv, accO[db][q4 * 4 + 1] * linv);
      const u32 hiw = cvtpk(accO[db][q4 * 4 + 2] * linv, accO[db][q4 * 4 + 3] * linv);
      *(u32*)(oT + l31 * 136 + dbase) = lo;
      *(u32*)(oT + l31 * 136 + dbase + 2) = hiw;
    }
  __syncthreads();
#pragma unroll
  for (int i = 0; i < 8; ++i) {
    const int cid = i * 64 + lane;
    const int qloc = cid >> 4;
    const int c = cid & 15;
    const bf16x8 val = *(const bf16x8*)(oT + qloc * 136 + c * 8);
    *(bf16x8*)(ao + (bS + qrow0 + qloc) * DIM_ + head * HD_ + c * 8) = val;
  }
}

// ---------- launch ----------
extern "C" void kernel_launch(void* const* d_in, const int* in_sizes, int n_in,
                              void* d_out, int out_size, void* d_ws, size_t ws_size,
                              hipStream_t stream) {
  const float* x  = (const float*)d_in[0];
  const float* wq = (const float*)d_in[2];
  const float* wk = (const float*)d_in[3];
  const float* wv = (const float*)d_in[4];
  const float* wo = (const float*)d_in[5];

  char* ws = (char*)d_ws;
  size_t off = 0;
  auto carve = [&](size_t bytes) { char* p = ws + off; off += bytes; return p; };
  u16* xb   = (u16*)carve((size_t)M_ * DIM_ * 2);
  u16* wqb  = (u16*)carve((size_t)DIM_ * DIM_ * 2);
  u16* wkb  = (u16*)carve((size_t)DIM_ * DIM_ * 2);
  u16* wvb  = (u16*)carve((size_t)DIM_ * DIM_ * 2);
  u16* wob  = (u16*)carve((size_t)DIM_ * DIM_ * 2);
  u16* qb   = (u16*)carve((size_t)M_ * DIM_ * 2);
  u16* kb   = (u16*)carve((size_t)M_ * DIM_ * 2);
  u16* vb   = (u16*)carve((size_t)M_ * DIM_ * 2);
  u16* aob  = (u16*)carve((size_t)M_ * DIM_ * 2);
  float* cosT = (float*)carve((size_t)S_ * 64 * 4);
  float* sinT = (float*)carve((size_t)S_ * 64 * 4);
  if (off > ws_size) return;

  convert_kernel<<<2048, 256, 0, stream>>>(x, xb, M_ * DIM_);
  convert_kernel<<<1024, 256, 0, stream>>>(wq, wqb, DIM_ * DIM_);
  convert_kernel<<<1024, 256, 0, stream>>>(wk, wkb, DIM_ * DIM_);
  convert_kernel<<<1024, 256, 0, stream>>>(wv, wvb, DIM_ * DIM_);
  convert_kernel<<<1024, 256, 0, stream>>>(wo, wob, DIM_ * DIM_);
  rope_table_kernel<<<512, 256, 0, stream>>>(cosT, sinT);

  gemm8_qkv_kernel<<<384, 512, 0, stream>>>(xb, wqb, wkb, wvb, qb, kb, vb);

  rope_apply_kernel<<<(B_ * S_ * H_ * 64) / 256, 256, 0, stream>>>(qb, cosT, sinT);
  rope_apply_kernel<<<(B_ * S_ * H_ * 64) / 256, 256, 0, stream>>>(kb, cosT, sinT);

  dim3 ga(S_ / 128, H_, B_);
  attn_kernel<<<ga, 256, 0, stream>>>(qb, kb, vb, aob);

  dim3 go(DIM_ / 128, M_ / 128);
  gemm_out_kernel<<<go, 256, 0, stream>>>(aob, wob, (float*)d_out);
}

// Round 4
// 283.521 us; speedup vs baseline: 1.3385x; 1.0388x over previous
//
#include <hip/hip_runtime.h>
#include <cstdint>

typedef unsigned short u16;
typedef uint32_t u32;
typedef __attribute__((ext_vector_type(8))) short bf16x8;
typedef __attribute__((ext_vector_type(4))) float f32x4;
typedef __attribute__((ext_vector_type(16))) float f32x16;

#define DIM_ 2048
#define S_   2048
#define B_   2
#define H_   16
#define HD_  128
#define M_   (B_ * S_)  // 4096

// ---------- scalar bf16 helpers (RNE) ----------
__device__ __forceinline__ u16 f2b(float f) {
  union { float f; uint32_t u; } v; v.f = f;
  uint32_t u = v.u;
  return (u16)((u + 0x7FFFu + ((u >> 16) & 1u)) >> 16);
}
__device__ __forceinline__ float b2f(u16 h) {
  union { uint32_t u; float f; } v; v.u = ((uint32_t)h) << 16;
  return v.f;
}

// pack 2 f32 -> 2 bf16 in one u32 (lo = first arg)
__device__ __forceinline__ u32 cvtpk(float lo, float hi) {
  u32 r;
  asm("v_cvt_pk_bf16_f32 %0, %1, %2" : "=v"(r) : "v"(lo), "v"(hi));
  return r;
}

// ---------- global -> LDS async copy (16B per lane, wave-uniform LDS base) ----------
typedef __attribute__((address_space(3))) u16 lds_u16_t;
typedef __attribute__((address_space(1))) const u16 glob_u16_t;

__device__ __forceinline__ void gload16(const u16* g, u16* l) {
  __builtin_amdgcn_global_load_lds((glob_u16_t*)g, (lds_u16_t*)l, 16, 0, 0);
}

// ---------- fp32 -> bf16 convert, 5 buffers in one launch ----------
__global__ void convert5_kernel(const float* __restrict__ x, const float* __restrict__ wq,
                                const float* __restrict__ wk, const float* __restrict__ wv,
                                const float* __restrict__ wo, u16* __restrict__ xb,
                                u16* __restrict__ wqb, u16* __restrict__ wkb,
                                u16* __restrict__ wvb, u16* __restrict__ wob) {
  const float* src;
  u16* dst;
  int n;
  switch (blockIdx.y) {
    case 0: src = x;  dst = xb;  n = M_ * DIM_;   break;
    case 1: src = wq; dst = wqb; n = DIM_ * DIM_; break;
    case 2: src = wk; dst = wkb; n = DIM_ * DIM_; break;
    case 3: src = wv; dst = wvb; n = DIM_ * DIM_; break;
    default: src = wo; dst = wob; n = DIM_ * DIM_; break;
  }
  int i = (blockIdx.x * blockDim.x + threadIdx.x) * 4;
  const int stride = gridDim.x * blockDim.x * 4;
  for (; i < n; i += stride) {
    float4 v = *reinterpret_cast<const float4*>(src + i);
    uint64_t p = (uint64_t)f2b(v.x) | ((uint64_t)f2b(v.y) << 16) |
                 ((uint64_t)f2b(v.z) << 32) | ((uint64_t)f2b(v.w) << 48);
    *reinterpret_cast<uint64_t*>(dst + i) = p;
  }
}

// ---------- RoPE tables: cos/sin [S][64] fp32 ----------
__global__ void rope_table_kernel(float* __restrict__ cosT, float* __restrict__ sinT) {
  int i = blockIdx.x * blockDim.x + threadIdx.x;
  if (i >= S_ * 64) return;
  int s = i >> 6, d = i & 63;
  float inv = powf(10000.0f, -(float)d * (1.0f / 64.0f));
  float ang = (float)s * inv;
  cosT[i] = cosf(ang);
  sinT[i] = sinf(ang);
}

// ---------- RoPE apply (in-place, rotate-half, D=128), q and k in one launch ----------
__global__ void rope_apply_kernel(u16* __restrict__ qb, u16* __restrict__ kb,
                                  const float* __restrict__ cosT,
                                  const float* __restrict__ sinT) {
  u16* buf = blockIdx.y ? kb : qb;
  int i = blockIdx.x * blockDim.x + threadIdx.x;  // over B*S*H*64
  if (i >= B_ * S_ * H_ * 64) return;
  int d = i & 63;
  int h = (i >> 6) & (H_ - 1);
  int row = i >> 10;        // b*S + s
  int s = row & (S_ - 1);
  u16* p = buf + (size_t)row * DIM_ + h * HD_ + d;
  float t1 = b2f(p[0]);
  float t2 = b2f(p[64]);
  float c = cosT[s * 64 + d];
  float sn = sinT[s * 64 + d];
  p[0]  = f2b(t1 * c - t2 * sn);
  p[64] = f2b(t2 * c + t1 * sn);
}

// ==================================================================================
// 8-phase GEMM, BM=256 x BN=128, BK=64: C = A[4096,2048] @ W[*,2048]^T.
// 512 thr = 8 waves (2M x 4N); wave tile 128x32; 2 phases/K-tile x 16 MFMA.
// LDS 96KB = 2 bufs x (A 256x64 | B 128x64), chunk-XOR swizzle (slot = chunk ^ row&7).
// Stage cadence (race-free via barrier ordering; counted vmcnt per guide T4):
//   P0(t): read A0,B(cur); stage A1(t+1)->buf^1;            vmcnt 6 (0 at t=NT-1)
//   P1(t): read A1(cur);   stage B(t+2),A0(t+2)->cur;       vmcnt 6 (2 at t=NT-2)
// Tile counts: QKV 16x16x3 = 768 blocks = 3 exact rounds of 256 CUs; O 256 = 1 round.
// ==================================================================================
#define NT_ 32  // 2048 / 64

template <bool OUTF32>
__device__ __forceinline__ void gemm256x128_body(const u16* __restrict__ A,
                                                 const u16* __restrict__ W, int mt, int nt,
                                                 u16* __restrict__ Cb, float* __restrict__ Cf) {
  __shared__ __align__(16) u16 lds[49152];  // [buf2][A 16384 | B 8192] u16 = 96 KB
  const int tid = threadIdx.x;
  const int lane = tid & 63;
  const int w = tid >> 6;
  const int wm = w >> 2, wn = w & 3;
  const int l15 = lane & 15, lg = lane >> 4;

  const u16* Ab = A + (size_t)(mt * 256) * DIM_;
  const u16* Bb = W + (size_t)(nt * 128) * DIM_;

  f32x4 acc[8][2];
#pragma unroll
  for (int i = 0; i < 8; ++i)
#pragma unroll
    for (int j = 0; j < 2; ++j) acc[i][j] = (f32x4){0.f, 0.f, 0.f, 0.f};

  // half = row-half of A (128 rows); 2 sweeps of 512 chunks (8KB each)
  auto stageA = [&](int buf, int half, int kt) {
#pragma unroll
    for (int s = 0; s < 2; ++s) {
      const int cb = s * 512 + w * 64;      // wave-uniform chunk base
      const int i = cb + lane;
      const int r = half * 128 + (i >> 3);  // row in A tile
      const int c = (i & 7) ^ (r & 7);      // inverse-swizzled source chunk
      gload16(Ab + (size_t)r * DIM_ + kt * 64 + c * 8,
              lds + buf * 24576 + half * 8192 + cb * 8);
    }
  };
  auto stageB = [&](int buf, int kt) {
#pragma unroll
    for (int s = 0; s < 2; ++s) {
      const int cb = s * 512 + w * 64;
      const int i = cb + lane;
      const int r = i >> 3;                 // row 0..127
      const int c = (i & 7) ^ (r & 7);
      gload16(Bb + (size_t)r * DIM_ + kt * 64 + c * 8,
              lds + buf * 24576 + 16384 + cb * 8);
    }
  };
  auto rdA = [&](int buf, int mh, int mi, int ks) -> bf16x8 {
    const int row = wm * 128 + mh * 64 + mi * 16 + l15;
    const int chunk = ((ks << 2) + lg) ^ (l15 & 7);
    return *(const bf16x8*)(lds + buf * 24576 + row * 64 + chunk * 8);
  };
  auto rdB = [&](int buf, int ni, int ks) -> bf16x8 {
    const int row = wn * 32 + ni * 16 + l15;
    const int chunk = ((ks << 2) + lg) ^ (l15 & 7);
    return *(const bf16x8*)(lds + buf * 24576 + 16384 + row * 64 + chunk * 8);
  };

  bf16x8 a[8], b[4];

  // P0: read A0+B of cur; MFMA acc[0..3]; stage A1(t+1); vmcnt wv then barrier
  auto phase0 = [&](int t, int cur, bool stg, int wv) {
#pragma unroll
    for (int ni = 0; ni < 2; ++ni)
#pragma unroll
      for (int ks = 0; ks < 2; ++ks) b[ni * 2 + ks] = rdB(cur, ni, ks);
#pragma unroll
    for (int mi = 0; mi < 4; ++mi)
#pragma unroll
      for (int ks = 0; ks < 2; ++ks) a[mi * 2 + ks] = rdA(cur, 0, mi, ks);
    if (stg) stageA(cur ^ 1, 1, t + 1);
    __builtin_amdgcn_s_barrier();
    asm volatile("s_waitcnt lgkmcnt(0)" ::: "memory");
    __builtin_amdgcn_sched_barrier(0);
    __builtin_amdgcn_s_setprio(1);
#pragma unroll
    for (int mi = 0; mi < 4; ++mi)
#pragma unroll
      for (int ni = 0; ni < 2; ++ni)
#pragma unroll
        for (int ks = 0; ks < 2; ++ks)
          acc[mi][ni] = __builtin_amdgcn_mfma_f32_16x16x32_bf16(a[mi * 2 + ks],
                                                                b[ni * 2 + ks],
                                                                acc[mi][ni], 0, 0, 0);
    __builtin_amdgcn_s_setprio(0);
    __builtin_amdgcn_sched_barrier(0);
    if (wv == 6) asm volatile("s_waitcnt vmcnt(6)" ::: "memory");
    else         asm volatile("s_waitcnt vmcnt(0)" ::: "memory");
    __builtin_amdgcn_sched_barrier(0);
    __builtin_amdgcn_s_barrier();
  };
  // P1: read A1 of cur; MFMA acc[4..7]; stage B(t+2)+A0(t+2); vmcnt wv then barrier
  auto phase1 = [&](int t, int cur, bool stg, int wv) {
#pragma unroll
    for (int mi = 0; mi < 4; ++mi)
#pragma unroll
      for (int ks = 0; ks < 2; ++ks) a[mi * 2 + ks] = rdA(cur, 1, mi, ks);
    if (stg) { stageB(cur, t + 2); stageA(cur, 0, t + 2); }
    __builtin_amdgcn_s_barrier();
    asm volatile("s_waitcnt lgkmcnt(0)" ::: "memory");
    __builtin_amdgcn_sched_barrier(0);
    __builtin_amdgcn_s_setprio(1);
#pragma unroll
    for (int mi = 0; mi < 4; ++mi)
#pragma unroll
      for (int ni = 0; ni < 2; ++ni)
#pragma unroll
        for (int ks = 0; ks < 2; ++ks)
          acc[4 + mi][ni] = __builtin_amdgcn_mfma_f32_16x16x32_bf16(a[mi * 2 + ks],
                                                                    b[ni * 2 + ks],
                                                                    acc[4 + mi][ni], 0, 0, 0);
    __builtin_amdgcn_s_setprio(0);
    if (wv >= 0) {
      __builtin_amdgcn_sched_barrier(0);
      if (wv == 6)      asm volatile("s_waitcnt vmcnt(6)" ::: "memory");
      else if (wv == 2) asm volatile("s_waitcnt vmcnt(2)" ::: "memory");
      else              asm volatile("s_waitcnt vmcnt(0)" ::: "memory");
      __builtin_amdgcn_sched_barrier(0);
      __builtin_amdgcn_s_barrier();
    }
  };

  // ---- prologue: A0(0),A1(0),B(0) + A0(1),B(1); A1(1) comes from P0(0) ----
  stageA(0, 0, 0);
  stageA(0, 1, 0);
  stageB(0, 0);
  stageA(1, 0, 1);
  stageB(1, 1);
  __builtin_amdgcn_sched_barrier(0);
  asm volatile("s_waitcnt vmcnt(4)" ::: "memory");  // tile0 fully landed
  __builtin_amdgcn_sched_barrier(0);
  __builtin_amdgcn_s_barrier();

  for (int t = 0; t < NT_ - 2; ++t) {
    const int cur = t & 1;
    phase0(t, cur, true, 6);
    phase1(t, cur, true, 6);
  }
  phase0(NT_ - 2, (NT_ - 2) & 1, true, 6);
  phase1(NT_ - 2, (NT_ - 2) & 1, false, 2);
  phase0(NT_ - 1, (NT_ - 1) & 1, false, 0);
  phase1(NT_ - 1, (NT_ - 1) & 1, false, -1);

  // ---- epilogue: D layout row=(lane>>4)*4+r, col=lane&15 per 16x16 frag ----
#pragma unroll
  for (int mi = 0; mi < 8; ++mi)
#pragma unroll
    for (int ni = 0; ni < 2; ++ni) {
      const int row = mt * 256 + wm * 128 + mi * 16 + lg * 4;
      const int col = nt * 128 + wn * 32 + ni * 16 + l15;
#pragma unroll
      for (int r = 0; r < 4; ++r) {
        if (OUTF32)
          Cf[(size_t)(row + r) * DIM_ + col] = acc[mi][ni][r];
        else
          Cb[(size_t)(row + r) * DIM_ + col] = f2b(acc[mi][ni][r]);
      }
    }
}

__global__ __launch_bounds__(512, 2) void gemm8_qkv_kernel(
    const u16* __restrict__ xb, const u16* __restrict__ wqb, const u16* __restrict__ wkb,
    const u16* __restrict__ wvb, u16* __restrict__ qb, u16* __restrict__ kb,
    u16* __restrict__ vb) {
  // XCD swizzle (768 % 8 == 0) + A-panel grouping: logical = mt*48 + z*16 + nt
  const int bid = blockIdx.x;
  const int logical = (bid & 7) * 96 + (bid >> 3);
  const int mt = logical / 48;
  const int rem = logical % 48;
  const int z = rem >> 4;
  const int nt = rem & 15;
  const u16* W = (z == 0) ? wqb : (z == 1) ? wkb : wvb;
  u16* out = (z == 0) ? qb : (z == 1) ? kb : vb;
  gemm256x128_body<false>(xb, W, mt, nt, out, nullptr);
}

__global__ __launch_bounds__(512, 2) void gemm8_out_kernel(const u16* __restrict__ aob,
                                                           const u16* __restrict__ wob,
                                                           float* __restrict__ C) {
  const int bid = blockIdx.x;  // 256 blocks = 1 exact round
  const int logical = (bid & 7) * 32 + (bid >> 3);
  const int mt = logical >> 4;
  const int nt = logical & 15;
  gemm256x128_body<true>(aob, wob, mt, nt, nullptr, C);
}

// ---------- causal flash attention, swapped-QK^T 32x32 structure ----------
#define CEXP 0.12751744f  /* (1/sqrt(128)) * log2(e) */

__global__ __launch_bounds__(256, 2) void attn_kernel(const u16* __restrict__ q,
                                                      const u16* __restrict__ k,
                                                      const u16* __restrict__ v,
                                                      u16* __restrict__ ao) {
  __shared__ __align__(16) u16 smem[17408];
  u16* kTl = smem;
  u16* vTl = smem + 8192;

  const int qt   = blockIdx.z ? (int)blockIdx.x : (int)(gridDim.x - 1 - blockIdx.x);
  const int head = blockIdx.y;
  const int b    = blockIdx.z;
  const int t = threadIdx.x;
  const int lane = t & 63;
  const int w = t >> 6;
  const int l31 = lane & 31;
  const int hi = lane >> 5;
  const int kxor = (lane & 7) << 3;
  const int qrow0 = qt * 128 + w * 32;
  const size_t bS = (size_t)b * S_;

  bf16x8 qf[8];
  {
    const u16* qrow = q + (bS + qrow0 + l31) * DIM_ + head * HD_;
#pragma unroll
    for (int st = 0; st < 8; ++st)
      qf[st] = *(const bf16x8*)(qrow + st * 16 + hi * 8);
  }

  f32x16 accO[4];
#pragma unroll
  for (int db = 0; db < 4; ++db)
#pragma unroll
    for (int r = 0; r < 16; ++r) accO[db][r] = 0.f;
  float m = -1e30f, l = 0.f;

  const int tmax_w = 2 * qt + (w >> 1);
  const int ttend = 2 * qt + 1;

  for (int tt = 0; tt <= ttend; ++tt) {
    __syncthreads();

    bf16x8 vv[4];
#pragma unroll
    for (int p = 0; p < 4; ++p) {
      const int dchunk = p * 4 + w;
      vv[p] = *(const bf16x8*)(v + (bS + tt * 64 + lane) * DIM_ + head * HD_ + dchunk * 8);
    }
#pragma unroll
    for (int p = 0; p < 4; ++p) {
      const int cb = p * 256 + w * 64;
      const int cid = cb + lane;
      const int kr = cid >> 4;
      const int cg = (cid & 15) ^ (kr & 7);
      gload16(k + (bS + tt * 64 + kr) * DIM_ + head * HD_ + cg * 8, kTl + cb * 8);
    }
#pragma unroll
    for (int p = 0; p < 4; ++p) {
      const int dchunk = p * 4 + w;
#pragma unroll
      for (int j = 0; j < 8; ++j) {
        const int d = dchunk * 8 + j;
        vTl[d * 64 + (lane ^ ((d & 7) << 3))] = (u16)vv[p][j];
      }
    }
    __syncthreads();

    if (tt <= tmax_w) {
      f32x16 sA, sB;
#pragma unroll
      for (int r = 0; r < 16; ++r) { sA[r] = 0.f; sB[r] = 0.f; }
      __builtin_amdgcn_s_setprio(1);
#pragma unroll
      for (int st = 0; st < 8; ++st) {
        const int dc = st * 16 + hi * 8;
        bf16x8 k0 = *(const bf16x8*)(kTl + l31 * 128 + (dc ^ kxor));
        bf16x8 k1 = *(const bf16x8*)(kTl + (32 + l31) * 128 + (dc ^ kxor));
        sA = __builtin_amdgcn_mfma_f32_32x32x16_bf16(k0, qf[st], sA, 0, 0, 0);
        sB = __builtin_amdgcn_mfma_f32_32x32x16_bf16(k1, qf[st], sB, 0, 0, 0);
      }
      __builtin_amdgcn_s_setprio(0);

      const int qg = qrow0 + l31;
      if (tt * 64 + 63 > qrow0) {
        const int kb = tt * 64 + 4 * hi;
#pragma unroll
        for (int r = 0; r < 16; ++r) {
          const int kg = kb + (r & 3) + 8 * (r >> 2);
          sA[r] = (kg <= qg) ? sA[r] : -1e30f;
          sB[r] = (kg + 32 <= qg) ? sB[r] : -1e30f;
        }
      }

      // tree max (depth ~log): was a 31-deep serial fmax chain
      float mx[8];
#pragma unroll
      for (int i = 0; i < 8; ++i)
        mx[i] = fmaxf(fmaxf(sA[i], sA[i + 8]), fmaxf(sB[i], sB[i + 8]));
#pragma unroll
      for (int i = 0; i < 4; ++i) mx[i] = fmaxf(mx[i], mx[i + 4]);
      float pm = fmaxf(fmaxf(mx[0], mx[1]), fmaxf(mx[2], mx[3]));
      pm = fmaxf(pm, __shfl_xor(pm, 32));
      const float mN = fmaxf(m, pm);
      if (!__all(pm - m <= 90.5f)) {  // T13 defer-max, THR=8 nat units
        const float osc = exp2f((m - mN) * CEXP);
        l *= osc;
#pragma unroll
        for (int db = 0; db < 4; ++db)
#pragma unroll
          for (int r = 0; r < 16; ++r) accO[db][r] *= osc;
        m = mN;
      }
      const float mc = m * CEXP;
      float lsv[4] = {0.f, 0.f, 0.f, 0.f};  // 4 chains instead of one 32-deep chain
#pragma unroll
      for (int r = 0; r < 16; ++r) {
        const float pa = exp2f(__builtin_fmaf(sA[r], CEXP, -mc));
        const float pb = exp2f(__builtin_fmaf(sB[r], CEXP, -mc));
        sA[r] = pa; sB[r] = pb;
        lsv[r & 3] += pa + pb;
      }
      float ls = (lsv[0] + lsv[1]) + (lsv[2] + lsv[3]);
      ls += __shfl_xor(ls, 32);
      l += ls;

#define PV_STEP(ARR, R0, ST2)                                                      \
      {                                                                            \
        u32 a0 = cvtpk(ARR[(R0) + 0], ARR[(R0) + 1]);                              \
        u32 a1 = cvtpk(ARR[(R0) + 2], ARR[(R0) + 3]);                              \
        u32 b0 = cvtpk(ARR[(R0) + 4], ARR[(R0) + 5]);                              \
        u32 b1 = cvtpk(ARR[(R0) + 6], ARR[(R0) + 7]);                              \
        asm("v_permlane32_swap_b32 %0, %1" : "+v"(a0), "+v"(b0));                  \
        asm("v_permlane32_swap_b32 %0, %1" : "+v"(a1), "+v"(b1));                  \
        union { u32 uu[4]; bf16x8 v8; } pf;                                        \
        pf.uu[0] = a0; pf.uu[1] = a1; pf.uu[2] = b0; pf.uu[3] = b1;                \
        const int ko = (ST2) * 16 + hi * 8;                                        \
        __builtin_amdgcn_s_setprio(1);                                             \
        _Pragma("unroll")                                                          \
        for (int db = 0; db < 4; ++db) {                                           \
          const int dr = db * 32 + l31;                                            \
          bf16x8 vf = *(const bf16x8*)(vTl + dr * 64 + (ko ^ kxor));               \
          accO[db] =                                                               \
              __builtin_amdgcn_mfma_f32_32x32x16_bf16(vf, pf.v8, accO[db], 0, 0, 0); \
        }                                                                          \
        __builtin_amdgcn_s_setprio(0);                                             \
      }
      PV_STEP(sA, 0, 0)
      PV_STEP(sA, 8, 1)
      PV_STEP(sB, 0, 2)
      PV_STEP(sB, 8, 3)
#undef PV_STEP
    }
  }

  __syncthreads();
  const float linv = 1.0f / l;
  u16* oT = smem + w * 4352;
#pragma unroll
  for (int db = 0; db < 4; ++db)
#pragma unroll
    for (int q4 = 0; q4 < 4; ++q4) {
      const int dbase = db * 32 + q4 * 8 + hi * 4;
      const u32 lo = cvtpk(accO[db][q4 * 4 + 0] * linv, accO[db][q4 * 4 + 1] * linv);
      const u32 hiw = cvtpk(accO[db][q4 * 4 + 2] * linv, accO[db][q4 * 4 + 3] * linv);
      *(u32*)(oT + l31 * 136 + dbase) = lo;
      *(u32*)(oT + l31 * 136 + dbase + 2) = hiw;
    }
  __syncthreads();
#pragma unroll
  for (int i = 0; i < 8; ++i) {
    const int cid = i * 64 + lane;
    const int qloc = cid >> 4;
    const int c = cid & 15;
    const bf16x8 val = *(const bf16x8*)(oT + qloc * 136 + c * 8);
    *(bf16x8*)(ao + (bS + qrow0 + qloc) * DIM_ + head * HD_ + c * 8) = val;
  }
}

// ---------- launch ----------
extern "C" void kernel_launch(void* const* d_in, const int* in_sizes, int n_in,
                              void* d_out, int out_size, void* d_ws, size_t ws_size,
                              hipStream_t stream) {
  const float* x  = (const float*)d_in[0];
  const float* wq = (const float*)d_in[2];
  const float* wk = (const float*)d_in[3];
  const float* wv = (const float*)d_in[4];
  const float* wo = (const float*)d_in[5];

  char* ws = (char*)d_ws;
  size_t off = 0;
  auto carve = [&](size_t bytes) { char* p = ws + off; off += bytes; return p; };
  u16* xb   = (u16*)carve((size_t)M_ * DIM_ * 2);
  u16* wqb  = (u16*)carve((size_t)DIM_ * DIM_ * 2);
  u16* wkb  = (u16*)carve((size_t)DIM_ * DIM_ * 2);
  u16* wvb  = (u16*)carve((size_t)DIM_ * DIM_ * 2);
  u16* wob  = (u16*)carve((size_t)DIM_ * DIM_ * 2);
  u16* qb   = (u16*)carve((size_t)M_ * DIM_ * 2);
  u16* kb   = (u16*)carve((size_t)M_ * DIM_ * 2);
  u16* vb   = (u16*)carve((size_t)M_ * DIM_ * 2);
  u16* aob  = (u16*)carve((size_t)M_ * DIM_ * 2);
  float* cosT = (float*)carve((size_t)S_ * 64 * 4);
  float* sinT = (float*)carve((size_t)S_ * 64 * 4);
  if (off > ws_size) return;

  dim3 gc(1024, 5);
  convert5_kernel<<<gc, 256, 0, stream>>>(x, wq, wk, wv, wo, xb, wqb, wkb, wvb, wob);
  rope_table_kernel<<<512, 256, 0, stream>>>(cosT, sinT);

  gemm8_qkv_kernel<<<768, 512, 0, stream>>>(xb, wqb, wkb, wvb, qb, kb, vb);

  dim3 gr((B_ * S_ * H_ * 64) / 256, 2);
  rope_apply_kernel<<<gr, 256, 0, stream>>>(qb, kb, cosT, sinT);

  dim3 ga(S_ / 128, H_, B_);
  attn_kernel<<<ga, 256, 0, stream>>>(qb, kb, vb, aob);

  gemm8_out_kernel<<<256, 512, 0, stream>>>(aob, wob, (float*)d_out);
}